// Round 4
// baseline (322.363 us; speedup 1.0000x reference)
//
#include <hip/hip_runtime.h>

typedef float  f32x4  __attribute__((ext_vector_type(4)));
typedef __bf16 bf16x8 __attribute__((ext_vector_type(8)));
typedef unsigned short u16x8 __attribute__((ext_vector_type(8)));
typedef unsigned short u16x4 __attribute__((ext_vector_type(4)));

#define DEV static __device__ __forceinline__

DEV unsigned short f2b(float f) {            // f32 -> bf16 (RNE)
  unsigned int u = __float_as_uint(f);
  u += 0x7fffu + ((u >> 16) & 1u);
  return (unsigned short)(u >> 16);
}
DEV float b2f(unsigned short h) { return __uint_as_float(((unsigned int)h) << 16); }

DEV f32x4 mfma16(bf16x8 a, bf16x8 b, f32x4 c) {
  return __builtin_amdgcn_mfma_f32_16x16x32_bf16(a, b, c, 0, 0, 0);
}

typedef __attribute__((address_space(1))) const unsigned int* gas_t;
typedef __attribute__((address_space(3))) unsigned int* las_t;
DEV void gl16(const void* g, void* l) {      // 16B global -> LDS (lane-scattered dest: base + lane*16)
  __builtin_amdgcn_global_load_lds((gas_t)g, (las_t)l, 16, 0, 0);
}

// ---------------------------------------------------------------- prep
__global__ __launch_bounds__(256) void k_prep(
    const float* __restrict__ Wq_comp, const float* __restrict__ Wkv_comp,
    const float* __restrict__ Wqc, const float* __restrict__ Wqr,
    const float* __restrict__ Wkc, const float* __restrict__ Wkr,
    const float* __restrict__ Wv,
    unsigned short* __restrict__ W1t, unsigned short* __restrict__ Wqt,
    unsigned short* __restrict__ Wkvt, float* __restrict__ ct, float* __restrict__ st) {
  int tid = blockIdx.x * 256 + threadIdx.x;
  if (tid < 131072) {                       // W1t
    int n = tid >> 8, k = tid & 255;
    float v = (n < 256) ? Wq_comp[k * 256 + n] : Wkv_comp[k * 256 + (n - 256)];
    W1t[tid] = f2b(v);
  } else if (tid < 196608) {                // Wqt
    int t2 = tid - 131072; int n = t2 >> 8, k = t2 & 255;
    float v = (n < 192) ? Wqc[k * 192 + n] : Wqr[k * 64 + (n - 192)];
    Wqt[t2] = f2b(v);
  } else if (tid < 327680) {                // Wkvt
    int t2 = tid - 196608; int n = t2 >> 8, k = t2 & 255;
    float v = (n < 192) ? Wkc[k * 192 + n]
             : (n < 256) ? Wkr[k * 64 + (n - 192)] : Wv[k * 256 + (n - 256)];
    Wkvt[t2] = f2b(v);
  } else if (tid < 393216) {                // rope table
    int t2 = tid - 327680; int t = t2 >> 5, i = t2 & 31;
    float theta = powf(10000.0f, -(float)i / 32.0f);
    float ang = (float)t * theta;
    ct[t2] = cosf(ang); st[t2] = sinf(ang);
  }
}

// ---------------------------------------------------------------- GEMM1: C12 = x @ W1 (tile 128x256)
__global__ __launch_bounds__(512, 2) void k_gemm1(const float* __restrict__ X,
    const unsigned short* __restrict__ Bt, unsigned short* __restrict__ C) {
  __shared__ __align__(16) unsigned short Ash[128 * 72];
  __shared__ __align__(16) unsigned short Bsh[256 * 72];
  const int nt2 = blockIdx.x, mt = blockIdx.y;
  const int tid = threadIdx.x;
  const int l = tid & 63, wv = tid >> 6, li = l & 15, g = l >> 4;
  const int wm = wv >> 2, wn = wv & 3;
  const f32x4 zf = {0.f, 0.f, 0.f, 0.f};
  f32x4 acc[4][4];
#pragma unroll
  for (int i = 0; i < 4; ++i)
#pragma unroll
    for (int j = 0; j < 4; ++j) acc[i][j] = zf;
  for (int kb = 0; kb < 256; kb += 64) {
    __syncthreads();
#pragma unroll
    for (int it = 0; it < 4; ++it) {        // A: 128x64 f32 -> bf16
      int idx = it * 512 + tid;
      int row = idx >> 4, c4 = (idx & 15) << 2;
      f32x4 v = *reinterpret_cast<const f32x4*>(X + (size_t)(mt * 128 + row) * 256 + kb + c4);
      u16x4 u = { f2b(v.x), f2b(v.y), f2b(v.z), f2b(v.w) };
      *reinterpret_cast<u16x4*>(&Ash[row * 72 + c4]) = u;
    }
#pragma unroll
    for (int it = 0; it < 4; ++it) {        // B: 256 rows of W1t
      int idx = it * 512 + tid;
      int row = idx >> 3, c8 = (idx & 7) << 3;
      *reinterpret_cast<u16x8*>(&Bsh[row * 72 + c8]) =
        *reinterpret_cast<const u16x8*>(Bt + (size_t)(nt2 * 256 + row) * 256 + kb + c8);
    }
    __syncthreads();
#pragma unroll
    for (int kc = 0; kc < 2; ++kc) {
      bf16x8 a[4], b[4];
#pragma unroll
      for (int mf = 0; mf < 4; ++mf)
        a[mf] = *reinterpret_cast<const bf16x8*>(&Ash[(wm * 64 + mf * 16 + li) * 72 + kc * 32 + g * 8]);
#pragma unroll
      for (int nf = 0; nf < 4; ++nf)
        b[nf] = *reinterpret_cast<const bf16x8*>(&Bsh[(wn * 64 + nf * 16 + li) * 72 + kc * 32 + g * 8]);
#pragma unroll
      for (int mf = 0; mf < 4; ++mf)
#pragma unroll
        for (int nf = 0; nf < 4; ++nf)
          acc[mf][nf] = mfma16(a[mf], b[nf], acc[mf][nf]);
    }
  }
#pragma unroll
  for (int mf = 0; mf < 4; ++mf)
#pragma unroll
    for (int nf = 0; nf < 4; ++nf)
#pragma unroll
      for (int r = 0; r < 4; ++r) {
        int row = mt * 128 + wm * 64 + mf * 16 + g * 4 + r;
        int col = nt2 * 256 + wn * 64 + nf * 16 + li;
        C[(size_t)row * 512 + col] = f2b(acc[mf][nf][r]);
      }
}

// ---------------------------------------------------------------- GEMM2: q/k/v (one 256-col group per sel) + RoPE
__global__ __launch_bounds__(512, 2) void k_gemm2(const unsigned short* __restrict__ C12,
    const unsigned short* __restrict__ Wqt, const unsigned short* __restrict__ Wkvt,
    unsigned short* __restrict__ q_ws, unsigned short* __restrict__ k_ws,
    float* __restrict__ kout, float* __restrict__ vout,
    const float* __restrict__ ct, const float* __restrict__ st) {
  __shared__ __align__(16) unsigned short Ash[128 * 72];
  __shared__ __align__(16) unsigned short Bsh[256 * 72];
  const int sel = blockIdx.x, mt = blockIdx.y;   // sel: 0=q 1=k 2=v
  const int tid = threadIdx.x;
  const int l = tid & 63, wv = tid >> 6, li = l & 15, g = l >> 4;
  const int wm = wv >> 2, wn = wv & 3;
  const int acol = (sel == 0) ? 0 : 256;
  const unsigned short* Wt = (sel == 0) ? Wqt : Wkvt;
  const int wrow = (sel == 2) ? 256 : 0;
  const f32x4 zf = {0.f, 0.f, 0.f, 0.f};
  f32x4 acc[4][4];
#pragma unroll
  for (int i = 0; i < 4; ++i)
#pragma unroll
    for (int j = 0; j < 4; ++j) acc[i][j] = zf;
  for (int kb = 0; kb < 256; kb += 64) {
    __syncthreads();
#pragma unroll
    for (int it = 0; it < 2; ++it) {        // A from C12 (128x64 bf16)
      int idx = it * 512 + tid;
      int row = idx >> 3, c8 = (idx & 7) << 3;
      *reinterpret_cast<u16x8*>(&Ash[row * 72 + c8]) =
        *reinterpret_cast<const u16x8*>(C12 + (size_t)(mt * 128 + row) * 512 + acol + kb + c8);
    }
#pragma unroll
    for (int it = 0; it < 4; ++it) {        // B: 256 rows
      int idx = it * 512 + tid;
      int row = idx >> 3, c8 = (idx & 7) << 3;
      *reinterpret_cast<u16x8*>(&Bsh[row * 72 + c8]) =
        *reinterpret_cast<const u16x8*>(Wt + (size_t)(wrow + row) * 256 + kb + c8);
    }
    __syncthreads();
#pragma unroll
    for (int kc = 0; kc < 2; ++kc) {
      bf16x8 a[4], b[4];
#pragma unroll
      for (int mf = 0; mf < 4; ++mf)
        a[mf] = *reinterpret_cast<const bf16x8*>(&Ash[(wm * 64 + mf * 16 + li) * 72 + kc * 32 + g * 8]);
#pragma unroll
      for (int nf = 0; nf < 4; ++nf)
        b[nf] = *reinterpret_cast<const bf16x8*>(&Bsh[(wn * 64 + nf * 16 + li) * 72 + kc * 32 + g * 8]);
#pragma unroll
      for (int mf = 0; mf < 4; ++mf)
#pragma unroll
        for (int nf = 0; nf < 4; ++nf)
          acc[mf][nf] = mfma16(a[mf], b[nf], acc[mf][nf]);
    }
  }
  // fused RoPE on local cols 192..255 (wn==3) for q (sel 0) and k (sel 1)
  if (sel < 2 && wn == 3) {
#pragma unroll
    for (int mf = 0; mf < 4; ++mf)
#pragma unroll
      for (int nf = 0; nf < 4; ++nf)
#pragma unroll
        for (int r = 0; r < 4; ++r) {
          float v = acc[mf][nf][r];
          float other = __shfl_xor(v, 1);
          int t = (mt * 128 + wm * 64 + mf * 16 + g * 4 + r) & 2047;
          int i = nf * 8 + (li >> 1);
          float c = ct[t * 32 + i], s = st[t * 32 + i];
          acc[mf][nf][r] = (li & 1) ? (other * s + v * c) : (v * c - other * s);
        }
  }
#pragma unroll
  for (int mf = 0; mf < 4; ++mf)
#pragma unroll
    for (int nf = 0; nf < 4; ++nf) {
      int cl = wn * 64 + nf * 16 + li;     // 0..255
#pragma unroll
      for (int r = 0; r < 4; ++r) {
        int row = mt * 128 + wm * 64 + mf * 16 + g * 4 + r;
        float val = acc[mf][nf][r];
        if (sel == 0) {
          q_ws[(size_t)row * 256 + cl] = f2b(val);
        } else if (sel == 1) {
          k_ws[(size_t)row * 256 + cl] = f2b(val);
          kout[(size_t)row * 256 + cl] = val;
        } else {
          vout[(size_t)row * 256 + cl] = val;
        }
      }
    }
}

// ---------------------------------------------------------------- V transpose: [b][t][d] f32 -> [b][d][t] bf16
__global__ __launch_bounds__(256) void k_vtrans(const float* __restrict__ vout,
                                                unsigned short* __restrict__ vt) {
  __shared__ float tile[32][33];
  const int dt = blockIdx.x, tt = blockIdx.y, b = blockIdx.z;
  const int tid = threadIdx.x;
#pragma unroll
  for (int it = 0; it < 4; ++it) {
    int idx = it * 256 + tid;
    int tr = idx >> 5, dc = idx & 31;
    tile[tr][dc] = vout[((size_t)b * 2048 + tt * 32 + tr) * 256 + dt * 32 + dc];
  }
  __syncthreads();
#pragma unroll
  for (int it = 0; it < 4; ++it) {
    int idx = it * 256 + tid;
    int dr = idx >> 5, tc = idx & 31;
    vt[((size_t)b * 256 + dt * 32 + dr) * 2048 + tt * 32 + tc] = f2b(tile[tc][dr]);
  }
}

// ---------------------------------------------------------------- flash attention v4
// 256 thr = 4 waves, M=32 q-rows/wave (2 m-frags), Q-tile 128, full D=256.
// K/V double-buffered via global_load_lds w/ source-pre-swizzle (linear LDS dest).
// Fixed-max softmax P=exp(s/16-8); split-P halves (2KB/wave); ones-MFMA row sum.
// grid(32 b, 8 p): wgid = b+32p -> batch pinned to XCD b%8; pairs (p, 15-p).
__global__ __launch_bounds__(256, 1) void k_attn(
    const unsigned short* __restrict__ q_ws, const unsigned short* __restrict__ k_ws,
    const unsigned short* __restrict__ vt_ws, float* __restrict__ out) {
  __shared__ __align__(16) unsigned short Kb[2][64 * 256];   // 32KB each, chunk-swizzled
  __shared__ __align__(16) unsigned short Vb[2][256 * 64];   // 32KB each, chunk-swizzled
  __shared__ __align__(16) unsigned short Psh[4][1024];      // per-wave 32q x 32kk (one half)
  const int b = blockIdx.x, p = blockIdx.y;
  const int tid = threadIdx.x;
  const int l = tid & 63, wv = tid >> 6, li = l & 15, g = l >> 4;
  const f32x4 zf = {0.f, 0.f, 0.f, 0.f};

  u16x8 ones_u = {0x3F80, 0x3F80, 0x3F80, 0x3F80, 0x3F80, 0x3F80, 0x3F80, 0x3F80};
  bf16x8 ones = *reinterpret_cast<bf16x8*>(&ones_u);

  const unsigned short* kbase = k_ws + (size_t)b * 2048 * 256;
  const unsigned short* vbase = vt_ws + (size_t)b * 256 * 2048;

  // stage tile t into buffer (K: rows 64 x 32 chunks; V: 256 d x 8 chunks).
  // LDS dest linear in chunk index; global src col pre-XOR'd so that
  // LDS[row][pc] = G[row][pc ^ (row&7)] (same involution applied on read).
#define STAGE(t, Kdst, Vdst)                                                          \
  {                                                                                   \
    const unsigned short* ks_ = kbase + (size_t)(t) * 64 * 256;                       \
    const unsigned short* vs_ = vbase + (size_t)(t) * 64;                             \
    _Pragma("unroll")                                                                 \
    for (int rnd = 0; rnd < 8; ++rnd) {                                               \
      int chunk = rnd * 256 + wv * 64 + l;                                            \
      int row = chunk >> 5, pc = chunk & 31;                                          \
      gl16(ks_ + (size_t)row * 256 + ((pc ^ (row & 7)) << 3),                         \
           (Kdst) + (size_t)(rnd * 256 + wv * 64) * 8);                               \
    }                                                                                 \
    _Pragma("unroll")                                                                 \
    for (int rnd = 0; rnd < 8; ++rnd) {                                               \
      int chunk = rnd * 256 + wv * 64 + l;                                            \
      int d = chunk >> 3, pc = chunk & 7;                                             \
      gl16(vs_ + (size_t)d * 2048 + ((pc ^ (d & 7)) << 3),                            \
           (Vdst) + (size_t)(rnd * 256 + wv * 64) * 8);                               \
    }                                                                                 \
  }

  for (int seg = 0; seg < 2; ++seg) {
    const int qt = seg ? (15 - p) : p;
    const int wq0 = qt * 128 + wv * 32;
    bf16x8 qf[2][8];
#pragma unroll
    for (int mf = 0; mf < 2; ++mf) {
      const unsigned short* qp = q_ws + ((size_t)b * 2048 + wq0 + mf * 16 + li) * 256;
#pragma unroll
      for (int kc = 0; kc < 8; ++kc)
        qf[mf][kc] = *reinterpret_cast<const bf16x8*>(qp + kc * 32 + g * 8);
    }

    f32x4 o[2][16];
#pragma unroll
    for (int i = 0; i < 2; ++i)
#pragma unroll
      for (int j2 = 0; j2 < 16; ++j2) o[i][j2] = zf;
    f32x4 ol[2] = {zf, zf};

    const int nj = 2 * qt + 2;
    STAGE(0, Kb[0], Vb[0]);
    __syncthreads();

    for (int j = 0; j < nj; ++j) {
      const int c = j & 1;
      if (j + 1 < nj) STAGE(j + 1, Kb[c ^ 1], Vb[c ^ 1]);

      if (j * 64 - qt * 128 <= wv * 32 + 31) {   // wave not fully masked
        // QK^T: 32 q rows x 64 k rows (B-fragments reused by both m-frags)
        f32x4 s[2][4];
#pragma unroll
        for (int mf = 0; mf < 2; ++mf)
#pragma unroll
          for (int nf = 0; nf < 4; ++nf) s[mf][nf] = zf;
#pragma unroll
        for (int kc = 0; kc < 8; ++kc) {
          int pc = (kc * 4 + g) ^ (li & 7);
#pragma unroll
          for (int nf = 0; nf < 4; ++nf) {
            bf16x8 bk = *reinterpret_cast<const bf16x8*>(&Kb[c][(nf * 16 + li) * 256 + pc * 8]);
            s[0][nf] = mfma16(qf[0][kc], bk, s[0][nf]);
            s[1][nf] = mfma16(qf[1][kc], bk, s[1][nf]);
          }
        }
        // softmax numerator + PV, in two kk-halves (split-P: 2KB/wave)
#pragma unroll
        for (int h = 0; h < 2; ++h) {
#pragma unroll
          for (int mf = 0; mf < 2; ++mf)
#pragma unroll
            for (int r = 0; r < 4; ++r) {
              const int q = mf * 16 + g * 4 + r;       // 0..31 wave-local
              const int qg = wv * 32 + q;              // tile-local q
#pragma unroll
              for (int nf2 = 0; nf2 < 2; ++nf2) {
                const int nf = h * 2 + nf2;
                float pv = __expf(__builtin_fmaf(s[mf][nf][r], 0.0625f, -8.0f));
                int kg = j * 64 + nf * 16 + li - qt * 128;
                if (kg > qg) pv = 0.f;
                int kkl = nf2 * 16 + li;
                Psh[wv][q * 32 + (((kkl >> 3) ^ (q & 3)) << 3) + (kkl & 7)] = f2b(pv);
              }
            }
          bf16x8 pa0 = *reinterpret_cast<const bf16x8*>(&Psh[wv][li * 32 + ((g ^ (li & 3)) << 3)]);
          bf16x8 pa1 = *reinterpret_cast<const bf16x8*>(&Psh[wv][(16 + li) * 32 + ((g ^ (li & 3)) << 3)]);
          ol[0] = mfma16(pa0, ones, ol[0]);
          ol[1] = mfma16(pa1, ones, ol[1]);
          int pcv = (h * 4 + g) ^ (li & 7);
#pragma unroll
          for (int nfd = 0; nfd < 16; ++nfd) {
            bf16x8 bv = *reinterpret_cast<const bf16x8*>(&Vb[c][(nfd * 16 + li) * 64 + pcv * 8]);
            o[0][nfd] = mfma16(pa0, bv, o[0][nfd]);
            o[1][nfd] = mfma16(pa1, bv, o[1][nfd]);
          }
        }
      }
      __syncthreads();   // drains vmcnt(0): prefetched tile landed; buf c free for next prefetch
    }

    // epilogue: 32 rows x 256 cols
#pragma unroll
    for (int mf = 0; mf < 2; ++mf)
#pragma unroll
      for (int r = 0; r < 4; ++r) {
        float inv = 1.0f / ol[mf][r];
        int qrow = wq0 + mf * 16 + g * 4 + r;
        float* op = out + ((size_t)b * 2048 + qrow) * 256;
#pragma unroll
        for (int nfd = 0; nfd < 16; ++nfd)
          op[nfd * 16 + li] = o[mf][nfd][r] * inv;
      }
  }
#undef STAGE
}

// ---------------------------------------------------------------- launch
extern "C" void kernel_launch(void* const* d_in, const int* in_sizes, int n_in,
                              void* d_out, int out_size, void* d_ws, size_t ws_size,
                              hipStream_t stream) {
  const float* x        = (const float*)d_in[0];
  const float* Wq_comp  = (const float*)d_in[1];
  const float* Wkv_comp = (const float*)d_in[2];
  const float* Wqc      = (const float*)d_in[3];
  const float* Wqr      = (const float*)d_in[4];
  const float* Wkc      = (const float*)d_in[5];
  const float* Wkr      = (const float*)d_in[6];
  const float* Wv       = (const float*)d_in[7];

  float* out  = (float*)d_out;            // [32][2048][256]
  float* kout = out + 16777216;           // k output (f32)
  float* vout = out + 33554432;           // v output (f32)

  if (ws_size < 135397376u) return;

  char* ws = (char*)d_ws;
  unsigned short* C12  = (unsigned short*)(ws);              // 64MB; later reused as vt
  unsigned short* vt   = (unsigned short*)(ws);              // [32][256][2048] bf16 (32MB)
  unsigned short* q_ws = (unsigned short*)(ws + 67108864);   // 32MB
  unsigned short* k_ws = (unsigned short*)(ws + 100663296);  // 32MB
  unsigned short* W1t  = (unsigned short*)(ws + 134217728);  // 512x256
  unsigned short* Wqt  = W1t + 131072;                       // 256x256
  unsigned short* Wkvt = Wqt + 65536;                        // 512x256
  float* ct = (float*)(Wkvt + 131072);                       // 2048x32
  float* st = ct + 65536;

  k_prep<<<1536, 256, 0, stream>>>(Wq_comp, Wkv_comp, Wqc, Wqr, Wkc, Wkr, Wv,
                                   W1t, Wqt, Wkvt, ct, st);
  k_gemm1<<<dim3(2, 512), 512, 0, stream>>>(x, W1t, C12);
  k_gemm2<<<dim3(3, 512), 512, 0, stream>>>(C12, Wqt, Wkvt, q_ws, k_ws, kout, vout, ct, st);
  k_vtrans<<<dim3(8, 64, 32), 256, 0, stream>>>(vout, vt);
  k_attn<<<dim3(32, 8), 256, 0, stream>>>(q_ws, k_ws, vt, out);
}